// Round 11
// baseline (432.379 us; speedup 1.0000x reference)
//
#include <hip/hip_runtime.h>
#include <hip/hip_bf16.h>

// Problem dims (fixed)
#define NROWS 8192   // N == M == 8192
#define DIM   512    // IN_FEATS == OUT_FEATS == 512

typedef short v8s __attribute__((ext_vector_type(8)));
typedef float v4f __attribute__((ext_vector_type(4)));
typedef float v16f __attribute__((ext_vector_type(16)));

#define ASM_VMCNT(n) asm volatile("s_waitcnt vmcnt(" #n ")" ::: "memory")
#define ASM_LGKM0    asm volatile("s_waitcnt lgkmcnt(0)" ::: "memory")
#define ASM_FENCE    asm volatile("" ::: "memory")
#define BAR          __builtin_amdgcn_s_barrier()

__device__ __forceinline__ short f2bf(float f) {
    union { float f; unsigned u; } v; v.f = f;
    unsigned r = (v.u + 0x7fffu + ((v.u >> 16) & 1u)) >> 16;
    return (short)r;
}

__device__ __forceinline__ void stage16(const void* g, void* l) {
    typedef __attribute__((address_space(1))) const unsigned GA;
    typedef __attribute__((address_space(3))) unsigned LA;
    __builtin_amdgcn_global_load_lds((GA*)(const unsigned*)g, (LA*)(unsigned*)l, 16, 0, 0);
}

// ---------------------------------------------------------------------------
// Cast f32 [R][C] -> bf16 transposed [C][R]
// ---------------------------------------------------------------------------
__global__ __launch_bounds__(256) void transpose_cast_kernel(
        const float* __restrict__ in, short* __restrict__ out, int R, int C) {
    __shared__ float t[32][33];
    const int lx = threadIdx.x & 31;
    const int ly = threadIdx.x >> 5;
    const int r0 = blockIdx.x * 32;
    const int c0 = blockIdx.y * 32;
#pragma unroll
    for (int p = 0; p < 4; ++p)
        t[ly + 8 * p][lx] = in[(size_t)(r0 + ly + 8 * p) * C + c0 + lx];
    __syncthreads();
#pragma unroll
    for (int p = 0; p < 4; ++p)
        out[(size_t)(c0 + ly + 8 * p) * R + r0 + lx] = f2bf(t[lx][ly + 8 * p]);
}

// ---------------------------------------------------------------------------
// H = cast_bf16(F) @ W ; z selects (feat_p -> Hp) or (feat_s -> Hs)
// ---------------------------------------------------------------------------
__global__ __launch_bounds__(512) void gemm1_kernel(
        const float* __restrict__ Fp, const float* __restrict__ Fs,
        const short* __restrict__ WT,
        short* __restrict__ Hp, short* __restrict__ Hs) {
    const float* F = blockIdx.z ? Fs : Fp;
    short* H = blockIdx.z ? Hs : Hp;
    const int lane = threadIdx.x & 63;
    const int wid  = threadIdx.x >> 6;          // 0..7
    const int lr = lane & 15, lg = lane >> 4;
    const int r0 = blockIdx.x * 128 + wid * 16; // gridDim.x = 64
    const int c0 = blockIdx.y * 256;            // gridDim.y = 2

    v8s a[16];
#pragma unroll
    for (int kk = 0; kk < 16; ++kk) {
        const float* ap = F + (size_t)(r0 + lr) * DIM + kk * 32 + lg * 8;
        float4 f0 = *(const float4*)ap;
        float4 f1 = *(const float4*)(ap + 4);
        v8s t;
        t[0] = f2bf(f0.x); t[1] = f2bf(f0.y); t[2] = f2bf(f0.z); t[3] = f2bf(f0.w);
        t[4] = f2bf(f1.x); t[5] = f2bf(f1.y); t[6] = f2bf(f1.z); t[7] = f2bf(f1.w);
        a[kk] = t;
    }

    for (int ctp = 0; ctp < 8; ++ctp) {
        const int cb = c0 + ctp * 32;
        v4f acc0 = {}, acc1 = {};
#pragma unroll
        for (int kk = 0; kk < 16; ++kk) {
            v8s b0 = *(const v8s*)(WT + (size_t)(cb + lr) * DIM + kk * 32 + lg * 8);
            v8s b1 = *(const v8s*)(WT + (size_t)(cb + 16 + lr) * DIM + kk * 32 + lg * 8);
            acc0 = __builtin_amdgcn_mfma_f32_16x16x32_bf16(a[kk], b0, acc0, 0, 0, 0);
            acc1 = __builtin_amdgcn_mfma_f32_16x16x32_bf16(a[kk], b1, acc1, 0, 0, 0);
        }
#pragma unroll
        for (int i = 0; i < 4; ++i) {
            H[(size_t)(r0 + lg * 4 + i) * DIM + cb + lr]      = f2bf(acc0[i]);
            H[(size_t)(r0 + lg * 4 + i) * DIM + cb + 16 + lr] = f2bf(acc1[i]);
        }
    }
}

// ---------------------------------------------------------------------------
// Fused kernel, 32x32x16 K-split phase A:
//   wave = (mh=wid>>2: 32 m-rows, jh=(wid>>1)&1: 32 j-cols, kh=wid&1: K-half)
//   afrag = 32 rows x 256 k = 64 VGPR; 1 LDS read -> 32x32x16 MFMA (2x FLOP
//   per byte vs 16x16x32) -> phase-A LDS reads halved (256->128 KB/jt).
//   kh-pairs exchange partial S halves through Pb (f32, balanced both ways).
// body(t): BAR_A; stage(t+1); phaseA 16x{read+mfma}; give-half->Pb; lgkm;
//   BAR_B; combine+relu+cvt (own half, f32); vmcnt(8)->phaseB(t-1) from Sb;
//   lgkm; BAR_C; write Sb(t); issue bF(t); lgkm; vmcnt(8).
// Phase B unchanged: wave owns 64 C-cols, 16x16x32, single Sb buffer.
// ---------------------------------------------------------------------------
#define JSPLIT 2
#define JT_PER_BLOCK (NROWS / 64 / JSPLIT)   // 64 j-tiles of 64

__device__ __forceinline__ void stage_full(const char* __restrict__ HsB,
        char* ringW, int j0, int tid) {
#pragma unroll
    for (int s = 0; s < 8; ++s) {
        const int L = s * 8192 + tid * 16;              // linear LDS byte offset
        const int row = L >> 10;                        // 1024 B per j-row
        const int c = (L & 1023) ^ ((row & 7) << 4);    // inverse swizzle (involution)
        stage16(HsB + ((size_t)(j0 + row) << 10) + c, ringW + L);
    }
}

__device__ __forceinline__ void load_bF(v8s (&bF)[8], const short* __restrict__ FsT,
        int j, int wid, int lr, int lg) {
#pragma unroll
    for (int ct = 0; ct < 4; ++ct)
#pragma unroll
        for (int kc2 = 0; kc2 < 2; ++kc2)
            bF[ct * 2 + kc2] = *(const v8s*)(FsT +
                (size_t)(wid * 64 + ct * 16 + lr) * NROWS + j + kc2 * 32 + lg * 8);
}

__device__ __forceinline__ void phase_b(const short (*SbR)[72], const v8s* bF,
        v4f (&accC)[16], int lr, int lg) {
    __builtin_amdgcn_s_setprio(1);
#pragma unroll
    for (int kc2 = 0; kc2 < 2; ++kc2)
#pragma unroll
        for (int mt = 0; mt < 4; ++mt) {
            v8s aS = *(const v8s*)&SbR[mt * 16 + lr][kc2 * 32 + lg * 8];
#pragma unroll
            for (int ct = 0; ct < 4; ++ct)
                accC[mt * 4 + ct] = __builtin_amdgcn_mfma_f32_16x16x32_bf16(
                    aS, bF[ct * 2 + kc2], accC[mt * 4 + ct], 0, 0, 0);
        }
    __builtin_amdgcn_s_setprio(0);
}

__global__ __launch_bounds__(512, 2) void fused_kernel(
        const short* __restrict__ Hp, const short* __restrict__ Hs,
        const short* __restrict__ FsT, float* __restrict__ Cacc,
        float* __restrict__ ssq) {
    __shared__ __align__(16) short HsL[2][64][512];   // 2 x 64KB ring
    __shared__ __align__(16) short Sb[64][72];        // 9KB S-tile (single)
    __shared__ __align__(16) float Pb[8][64][8];      // 16KB partial exchange

    const int tid  = threadIdx.x;
    const int lane = tid & 63;
    const int wid  = tid >> 6;
    const int lr = lane & 15, lg = lane >> 4;     // phase B indices
    const int l31 = lane & 31, l5 = lane >> 5;    // phase A indices
    const int kh = wid & 1;                       // K-half (0..1)
    const int jh = (wid >> 1) & 1;                // j-half (0..1), 32 cols
    const int mh = wid >> 2;                      // m-half (0..1), 32 rows

    // XCD-aware swizzle: 256 blocks, 8 XCDs -> contiguous chunks of 32
    const int nwg = gridDim.x * gridDim.y;
    const int bid = blockIdx.x + gridDim.x * blockIdx.y;
    const int cpx = nwg >> 3;
    const int swz = (bid & 7) * cpx + (bid >> 3);
    const int bx = swz % gridDim.x;
    const int by = swz / gridDim.x;

    const int m0  = bx * 64;
    const int jt0 = by * JT_PER_BLOCK;

    // A-fragments (32x32x16): rows m0+mh*32+l31, k = kh*256 + kc*16 + l5*8
    v8s afrag[16];
#pragma unroll
    for (int kc = 0; kc < 16; ++kc)
        afrag[kc] = *(const v8s*)(Hp +
            (size_t)(m0 + mh * 32 + l31) * DIM + kh * 256 + kc * 16 + l5 * 8);

    v4f accC[16] = {};
    v8s bF[8];
    float ssq_l = 0.f;

    stage_full((const char*)Hs, (char*)&HsL[0][0][0], jt0 * 64, tid);
    ASM_VMCNT(0);   // afrag + jt0 staging drained

    const int xo2 = (l31 & 7) << 4;
    const int colbase = kh * 512 + l5 * 16;   // byte offset within 1KB k-row

    for (int t = 0; t < JT_PER_BLOCK; ++t) {
        const int jcur  = (jt0 + t) * 64;
        const int jnext = (t + 1 < JT_PER_BLOCK) ? jcur + 64 : jt0 * 64;
        const char* ringR = (const char*)&HsL[t & 1][0][0];
        char*       ringW = (char*)&HsL[(t + 1) & 1][0][0];

        BAR;   // BAR_A: ring[t&1] staged; Sb(t-1) published; Pb free
        ASM_FENCE;
        stage_full((const char*)Hs, ringW, jnext, tid);

        // ---- phase A(t): partial S[mh*32..+32][jh*32..+32] over K-half kh
        v16f pacc = {};
        {
            const char* rb = ringR + (size_t)(jh * 32 + l31) * 1024;
            __builtin_amdgcn_s_setprio(1);
#pragma unroll
            for (int kc = 0; kc < 16; ++kc) {
                v8s hb = *(const v8s*)(rb + ((colbase + kc * 32) ^ xo2));
                pacc = __builtin_amdgcn_mfma_f32_32x32x16_bf16(afrag[kc], hb, pacc, 0, 0, 0);
            }
            __builtin_amdgcn_s_setprio(0);
        }

        // ---- give the half we don't own to the kh-partner
        {
            float* gp = &Pb[wid][lane][0];
            if (kh == 0) {
                v4f g0 = {pacc[8], pacc[9], pacc[10], pacc[11]};
                v4f g1 = {pacc[12], pacc[13], pacc[14], pacc[15]};
                *(v4f*)gp = g0; *(v4f*)(gp + 4) = g1;
            } else {
                v4f g0 = {pacc[0], pacc[1], pacc[2], pacc[3]};
                v4f g1 = {pacc[4], pacc[5], pacc[6], pacc[7]};
                *(v4f*)gp = g0; *(v4f*)(gp + 4) = g1;
            }
        }
        ASM_LGKM0; BAR;   // BAR_B: Pb published; ring reads done

        // ---- combine own half (f32) + relu + ssq + cvt
        short sb16[8];
        {
            const float* pp = &Pb[wid ^ 1][lane][0];
            v4f q0 = *(const v4f*)pp;
            v4f q1 = *(const v4f*)(pp + 4);
            float sv[8];
            if (kh == 0) {
                sv[0] = pacc[0] + q0[0]; sv[1] = pacc[1] + q0[1];
                sv[2] = pacc[2] + q0[2]; sv[3] = pacc[3] + q0[3];
                sv[4] = pacc[4] + q1[0]; sv[5] = pacc[5] + q1[1];
                sv[6] = pacc[6] + q1[2]; sv[7] = pacc[7] + q1[3];
            } else {
                sv[0] = pacc[8]  + q0[0]; sv[1] = pacc[9]  + q0[1];
                sv[2] = pacc[10] + q0[2]; sv[3] = pacc[11] + q0[3];
                sv[4] = pacc[12] + q1[0]; sv[5] = pacc[13] + q1[1];
                sv[6] = pacc[14] + q1[2]; sv[7] = pacc[15] + q1[3];
            }
#pragma unroll
            for (int e = 0; e < 8; ++e) {
                float v = fmaxf(sv[e], 0.f);
                ssq_l += v * v;
                sb16[e] = f2bf(v);
            }
        }

        // ---- phase B(t-1): Sb still holds S(t-1); bF(t-1) landed
        if (t > 0) {
            ASM_VMCNT(8);   // drains bF(t-1) (oldest 8); stage(t+1) stays
            phase_b(Sb, bF, accC, lr, lg);
        }
        ASM_LGKM0; BAR;     // BAR_C: Sb(t-1) reads + Pb reads done

        // ---- write Sb(t): C/D layout rows (m74/m101): r=(E&3)+8*(E>>2)+4*l5
        {
            const int cb = jh * 32 + l31;
            if (kh == 0) {
#pragma unroll
                for (int e = 0; e < 8; ++e)
                    Sb[mh * 32 + (e & 3) + 8 * (e >> 2) + 4 * l5][cb] = sb16[e];
            } else {
#pragma unroll
                for (int e = 0; e < 8; ++e)
                    Sb[mh * 32 + 16 + (e & 3) + 8 * (e >> 2) + 4 * l5][cb] = sb16[e];
            }
        }

        // ---- issue bF(t) for next body (rides across BAR_A)
        ASM_FENCE;
        load_bF(bF, FsT, jcur, wid, lr, lg);
        ASM_LGKM0;      // Sb writes drained (publish at next BAR_A)
        ASM_VMCNT(8);   // stage(t+1) retired; bF(t) stays in flight
    }

    // ---- final phase B for t = JT-1 (bF already in flight)
    BAR;
    ASM_VMCNT(0);
    phase_b(Sb, bF, accC, lr, lg);

    // ---- epilogue
    float w = ssq_l;
#pragma unroll
    for (int off = 32; off; off >>= 1) w += __shfl_down(w, off);
    if (lane == 0) atomicAdd(ssq, w);

#pragma unroll
    for (int mt = 0; mt < 4; ++mt)
#pragma unroll
        for (int ct = 0; ct < 4; ++ct)
#pragma unroll
            for (int i = 0; i < 4; ++i)
                atomicAdd(&Cacc[(size_t)(m0 + mt * 16 + lg * 4 + i) * DIM +
                                wid * 64 + ct * 16 + lr],
                          accC[mt * 4 + ct][i]);
}

// ---------------------------------------------------------------------------
__global__ __launch_bounds__(256) void scale_kernel(float* __restrict__ C,
                                                    const float* __restrict__ ssq) {
    const float rs = 1.0f / sqrtf(*ssq);
    const size_t i = (size_t)blockIdx.x * blockDim.x + threadIdx.x;
    float4* p = (float4*)C;
    float4 v = p[i];
    v.x *= rs; v.y *= rs; v.z *= rs; v.w *= rs;
    p[i] = v;
}

// ---------------------------------------------------------------------------
extern "C" void kernel_launch(void* const* d_in, const int* in_sizes, int n_in,
                              void* d_out, int out_size, void* d_ws, size_t ws_size,
                              hipStream_t stream) {
    const float* feat_p   = (const float*)d_in[0];
    const float* feat_s   = (const float*)d_in[1];
    const float* weight_a = (const float*)d_in[2];

    char* ws = (char*)d_ws;
    float* ssqp = (float*)ws;                                  // 4 B
    short* WT   = (short*)(ws + 512);                          // 512 KB
    short* Hp   = (short*)(ws + 512 + 524288);                 // 8 MB
    short* Hs   = (short*)(ws + 512 + 524288 + 8388608);       // 8 MB
    short* FsT  = (short*)(ws + 512 + 524288 + 16777216);      // 8 MB [DIM][NROWS]

    transpose_cast_kernel<<<dim3(DIM / 32, DIM / 32), 256, 0, stream>>>(weight_a, WT, DIM, DIM);
    transpose_cast_kernel<<<dim3(NROWS / 32, DIM / 32), 256, 0, stream>>>(feat_s, FsT, NROWS, DIM);

    gemm1_kernel<<<dim3(NROWS / 128, 2, 2), 512, 0, stream>>>(
        feat_p, feat_s, WT, Hp, Hs);

    hipMemsetAsync(d_out, 0, (size_t)out_size * sizeof(float), stream);
    hipMemsetAsync(ssqp, 0, sizeof(float), stream);

    fused_kernel<<<dim3(NROWS / 64, JSPLIT), 512, 0, stream>>>(Hp, Hs, FsT, (float*)d_out, ssqp);

    scale_kernel<<<(out_size / 4 + 255) / 256, 256, 0, stream>>>((float*)d_out, ssqp);
}

// Round 12
// 392.821 us; speedup vs baseline: 1.1007x; 1.1007x over previous
//
#include <hip/hip_runtime.h>
#include <hip/hip_bf16.h>

// Problem dims (fixed)
#define NROWS 8192   // N == M == 8192
#define DIM   512    // IN_FEATS == OUT_FEATS == 512

typedef short v8s __attribute__((ext_vector_type(8)));
typedef float v4f __attribute__((ext_vector_type(4)));

#define ASM_VMCNT(n) asm volatile("s_waitcnt vmcnt(" #n ")" ::: "memory")
#define ASM_LGKM0    asm volatile("s_waitcnt lgkmcnt(0)" ::: "memory")
#define ASM_FENCE    asm volatile("" ::: "memory")
#define BAR          __builtin_amdgcn_s_barrier()

__device__ __forceinline__ short f2bf(float f) {
    union { float f; unsigned u; } v; v.f = f;
    unsigned r = (v.u + 0x7fffu + ((v.u >> 16) & 1u)) >> 16;
    return (short)r;
}

__device__ __forceinline__ void stage16(const void* g, void* l) {
    typedef __attribute__((address_space(1))) const unsigned GA;
    typedef __attribute__((address_space(3))) unsigned LA;
    __builtin_amdgcn_global_load_lds((GA*)(const unsigned*)g, (LA*)(unsigned*)l, 16, 0, 0);
}

// ---------------------------------------------------------------------------
// Cast f32 [R][C] -> bf16 transposed [C][R]
// ---------------------------------------------------------------------------
__global__ __launch_bounds__(256) void transpose_cast_kernel(
        const float* __restrict__ in, short* __restrict__ out, int R, int C) {
    __shared__ float t[32][33];
    const int lx = threadIdx.x & 31;
    const int ly = threadIdx.x >> 5;
    const int r0 = blockIdx.x * 32;
    const int c0 = blockIdx.y * 32;
#pragma unroll
    for (int p = 0; p < 4; ++p)
        t[ly + 8 * p][lx] = in[(size_t)(r0 + ly + 8 * p) * C + c0 + lx];
    __syncthreads();
#pragma unroll
    for (int p = 0; p < 4; ++p)
        out[(size_t)(c0 + ly + 8 * p) * R + r0 + lx] = f2bf(t[lx][ly + 8 * p]);
}

// ---------------------------------------------------------------------------
// H = cast_bf16(F) @ W ; z selects (feat_p -> Hp) or (feat_s -> Hs)
// ---------------------------------------------------------------------------
__global__ __launch_bounds__(512) void gemm1_kernel(
        const float* __restrict__ Fp, const float* __restrict__ Fs,
        const short* __restrict__ WT,
        short* __restrict__ Hp, short* __restrict__ Hs) {
    const float* F = blockIdx.z ? Fs : Fp;
    short* H = blockIdx.z ? Hs : Hp;
    const int lane = threadIdx.x & 63;
    const int wid  = threadIdx.x >> 6;          // 0..7
    const int lr = lane & 15, lg = lane >> 4;
    const int r0 = blockIdx.x * 128 + wid * 16; // gridDim.x = 64
    const int c0 = blockIdx.y * 256;            // gridDim.y = 2

    v8s a[16];
#pragma unroll
    for (int kk = 0; kk < 16; ++kk) {
        const float* ap = F + (size_t)(r0 + lr) * DIM + kk * 32 + lg * 8;
        float4 f0 = *(const float4*)ap;
        float4 f1 = *(const float4*)(ap + 4);
        v8s t;
        t[0] = f2bf(f0.x); t[1] = f2bf(f0.y); t[2] = f2bf(f0.z); t[3] = f2bf(f0.w);
        t[4] = f2bf(f1.x); t[5] = f2bf(f1.y); t[6] = f2bf(f1.z); t[7] = f2bf(f1.w);
        a[kk] = t;
    }

    for (int ctp = 0; ctp < 8; ++ctp) {
        const int cb = c0 + ctp * 32;
        v4f acc0 = {}, acc1 = {};
#pragma unroll
        for (int kk = 0; kk < 16; ++kk) {
            v8s b0 = *(const v8s*)(WT + (size_t)(cb + lr) * DIM + kk * 32 + lg * 8);
            v8s b1 = *(const v8s*)(WT + (size_t)(cb + 16 + lr) * DIM + kk * 32 + lg * 8);
            acc0 = __builtin_amdgcn_mfma_f32_16x16x32_bf16(a[kk], b0, acc0, 0, 0, 0);
            acc1 = __builtin_amdgcn_mfma_f32_16x16x32_bf16(a[kk], b1, acc1, 0, 0, 0);
        }
#pragma unroll
        for (int i = 0; i < 4; ++i) {
            H[(size_t)(r0 + lg * 4 + i) * DIM + cb + lr]      = f2bf(acc0[i]);
            H[(size_t)(r0 + lg * 4 + i) * DIM + cb + 16 + lr] = f2bf(acc1[i]);
        }
    }
}

// ---------------------------------------------------------------------------
// Fused kernel, 128-row M-tile (R9 wave economics, half the stage/bF traffic):
//   block = 128 m-rows x JSPLIT j-range; grid (64, 4) = 256 blocks = 1/CU.
//   ring[2] = two full 64x512 Hs jt-tiles (128 KB, XOR-swizzled storage)
//   Sb = single 128x64 bf16 S-tile (phase B reads it in-body)
// body(t): BAR; issue bF(t); stage(t+1);
//          phaseA(t): wave=16 m-rows, all 64 j (4 subtiles x 16 kk, 4 indep
//          chains); relu->Sb; lgkm0; BAR; vmcnt(8) [bF landed, stage in
//          flight]; phaseB(t): 64 MFMA into accC[32] (AGPR); vmcnt(0).
// Per-wave regs: afrag 64 + bF 32 + s[] 16 + addr ~ 125 arch; accC 128 AGPR.
// ---------------------------------------------------------------------------
#define MTILE  128
#define JSPLIT 4
#define JT_PER_BLOCK (NROWS / 64 / JSPLIT)   // 32 j-tiles of 64

__device__ __forceinline__ void stage_full(const char* __restrict__ HsB,
        char* ringW, int j0, int tid) {
#pragma unroll
    for (int s = 0; s < 8; ++s) {
        const int L = s * 8192 + tid * 16;              // linear LDS byte offset
        const int row = L >> 10;                        // 1024 B per j-row
        const int c = (L & 1023) ^ ((row & 7) << 4);    // inverse swizzle (involution)
        stage16(HsB + ((size_t)(j0 + row) << 10) + c, ringW + L);
    }
}

__device__ __forceinline__ void load_bF(v8s (&bF)[8], const short* __restrict__ FsT,
        int j, int wid, int lr, int lg) {
#pragma unroll
    for (int ct = 0; ct < 4; ++ct)
#pragma unroll
        for (int kc2 = 0; kc2 < 2; ++kc2)
            bF[ct * 2 + kc2] = *(const v8s*)(FsT +
                (size_t)(wid * 64 + ct * 16 + lr) * NROWS + j + kc2 * 32 + lg * 8);
}

__global__ __launch_bounds__(512, 2) void fused_kernel(
        const short* __restrict__ Hp, const short* __restrict__ Hs,
        const short* __restrict__ FsT, float* __restrict__ Cacc,
        float* __restrict__ ssq) {
    __shared__ __align__(16) short HsL[2][64][512];   // 2 x 64KB ring
    __shared__ __align__(16) short Sb[128][72];       // 18KB S-tile (single)

    const int tid  = threadIdx.x;
    const int lane = tid & 63;
    const int wid  = tid >> 6;                 // 0..7: m-strip AND C-col block
    const int lr = lane & 15, lg = lane >> 4;

    // XCD-aware swizzle: 256 blocks, 8 XCDs -> contiguous chunks of 32
    const int nwg = gridDim.x * gridDim.y;
    const int bid = blockIdx.x + gridDim.x * blockIdx.y;
    const int cpx = nwg >> 3;
    const int swz = (bid & 7) * cpx + (bid >> 3);
    const int bx = swz % gridDim.x;
    const int by = swz / gridDim.x;

    const int m0  = bx * MTILE;
    const int jt0 = by * JT_PER_BLOCK;

    // A-fragments: 16 Hp rows (strip wid) x full K=512 -> 64 VGPR
    v8s afrag[16];
#pragma unroll
    for (int kk = 0; kk < 16; ++kk)
        afrag[kk] = *(const v8s*)(Hp +
            (size_t)(m0 + wid * 16 + lr) * DIM + kk * 32 + lg * 8);

    v4f accC[32] = {};
    v8s bF[8];
    float ssq_l = 0.f;

    stage_full((const char*)Hs, (char*)&HsL[0][0][0], jt0 * 64, tid);
    ASM_VMCNT(0);   // afrag + jt0 staging drained

    const int xo = (lr & 7) << 4;

    for (int t = 0; t < JT_PER_BLOCK; ++t) {
        const int jcur  = (jt0 + t) * 64;
        const int jnext = (t + 1 < JT_PER_BLOCK) ? jcur + 64 : jt0 * 64;
        const char* ringR = (const char*)&HsL[t & 1][0][0];
        char*       ringW = (char*)&HsL[(t + 1) & 1][0][0];

        BAR;   // ring[t&1] staged by all; prev body's Sb reads done
        ASM_FENCE;

        // issue bF(t) (oldest in queue; consumed after phase A)
        load_bF(bF, FsT, jcur, wid, lr, lg);
        ASM_FENCE;   // pin vmem order: bF then stage DMAs
        stage_full((const char*)Hs, ringW, jnext, tid);

        // ---- phase A(t): S[wid*16..+16][0..64] over K=512 (4 indep chains)
        v4f s[4] = {};
        {
            __builtin_amdgcn_s_setprio(1);
#pragma unroll
            for (int kk = 0; kk < 16; ++kk) {
                const int off = (kk * 64 + lg * 16) ^ xo;
#pragma unroll
                for (int ct = 0; ct < 4; ++ct) {
                    v8s hb = *(const v8s*)(ringR + (size_t)(ct * 16 + lr) * 1024 + off);
                    s[ct] = __builtin_amdgcn_mfma_f32_16x16x32_bf16(afrag[kk], hb, s[ct], 0, 0, 0);
                }
            }
            __builtin_amdgcn_s_setprio(0);
        }

        // ---- relu + ssq + Sb write (rows wid*16.., cols 0..64)
#pragma unroll
        for (int ct = 0; ct < 4; ++ct)
#pragma unroll
            for (int i = 0; i < 4; ++i) {
                float v = fmaxf(s[ct][i], 0.f);
                ssq_l += v * v;
                Sb[wid * 16 + lg * 4 + i][ct * 16 + lr] = f2bf(v);
            }
        ASM_LGKM0; BAR;   // Sb complete & visible; ring reads done

        // ---- phase B(t): C[128 rows][wid*64..+64] += S @ Fs
        ASM_VMCNT(8);     // bF(t) landed; stage(t+1) stays in flight
        __builtin_amdgcn_s_setprio(1);
#pragma unroll
        for (int kc2 = 0; kc2 < 2; ++kc2)
#pragma unroll
            for (int mt = 0; mt < 8; ++mt) {
                v8s aS = *(const v8s*)&Sb[mt * 16 + lr][kc2 * 32 + lg * 8];
#pragma unroll
                for (int ct = 0; ct < 4; ++ct)
                    accC[mt * 4 + ct] = __builtin_amdgcn_mfma_f32_16x16x32_bf16(
                        aS, bF[ct * 2 + kc2], accC[mt * 4 + ct], 0, 0, 0);
            }
        __builtin_amdgcn_s_setprio(0);

        ASM_VMCNT(0);     // stage(t+1) landed before next BAR
    }

    // ---- epilogue
    float w = ssq_l;
#pragma unroll
    for (int off = 32; off; off >>= 1) w += __shfl_down(w, off);
    if (lane == 0) atomicAdd(ssq, w);

#pragma unroll
    for (int mt = 0; mt < 8; ++mt)
#pragma unroll
        for (int ct = 0; ct < 4; ++ct)
#pragma unroll
            for (int i = 0; i < 4; ++i)
                atomicAdd(&Cacc[(size_t)(m0 + mt * 16 + lg * 4 + i) * DIM +
                                wid * 64 + ct * 16 + lr],
                          accC[mt * 4 + ct][i]);
}

// ---------------------------------------------------------------------------
__global__ __launch_bounds__(256) void scale_kernel(float* __restrict__ C,
                                                    const float* __restrict__ ssq) {
    const float rs = 1.0f / sqrtf(*ssq);
    const size_t i = (size_t)blockIdx.x * blockDim.x + threadIdx.x;
    float4* p = (float4*)C;
    float4 v = p[i];
    v.x *= rs; v.y *= rs; v.z *= rs; v.w *= rs;
    p[i] = v;
}

// ---------------------------------------------------------------------------
extern "C" void kernel_launch(void* const* d_in, const int* in_sizes, int n_in,
                              void* d_out, int out_size, void* d_ws, size_t ws_size,
                              hipStream_t stream) {
    const float* feat_p   = (const float*)d_in[0];
    const float* feat_s   = (const float*)d_in[1];
    const float* weight_a = (const float*)d_in[2];

    char* ws = (char*)d_ws;
    float* ssqp = (float*)ws;                                  // 4 B
    short* WT   = (short*)(ws + 512);                          // 512 KB
    short* Hp   = (short*)(ws + 512 + 524288);                 // 8 MB
    short* Hs   = (short*)(ws + 512 + 524288 + 8388608);       // 8 MB
    short* FsT  = (short*)(ws + 512 + 524288 + 16777216);      // 8 MB [DIM][NROWS]

    transpose_cast_kernel<<<dim3(DIM / 32, DIM / 32), 256, 0, stream>>>(weight_a, WT, DIM, DIM);
    transpose_cast_kernel<<<dim3(NROWS / 32, DIM / 32), 256, 0, stream>>>(feat_s, FsT, NROWS, DIM);

    gemm1_kernel<<<dim3(NROWS / 128, 2, 2), 512, 0, stream>>>(
        feat_p, feat_s, WT, Hp, Hs);

    hipMemsetAsync(d_out, 0, (size_t)out_size * sizeof(float), stream);
    hipMemsetAsync(ssqp, 0, sizeof(float), stream);

    fused_kernel<<<dim3(NROWS / MTILE, JSPLIT), 512, 0, stream>>>(
        Hp, Hs, FsT, (float*)d_out, ssqp);

    scale_kernel<<<(out_size / 4 + 255) / 256, 256, 0, stream>>>((float*)d_out, ssqp);
}

// Round 13
// 359.734 us; speedup vs baseline: 1.2019x; 1.0920x over previous
//
#include <hip/hip_runtime.h>
#include <hip/hip_bf16.h>

// Problem dims (fixed)
#define NROWS 8192   // N == M == 8192
#define DIM   512    // IN_FEATS == OUT_FEATS == 512

typedef short v8s __attribute__((ext_vector_type(8)));
typedef float v4f __attribute__((ext_vector_type(4)));

#define ASM_VMCNT(n) asm volatile("s_waitcnt vmcnt(" #n ")" ::: "memory")
#define ASM_LGKM0    asm volatile("s_waitcnt lgkmcnt(0)" ::: "memory")
#define ASM_FENCE    asm volatile("" ::: "memory")
#define BAR          __builtin_amdgcn_s_barrier()

__device__ __forceinline__ short f2bf(float f) {
    union { float f; unsigned u; } v; v.f = f;
    unsigned r = (v.u + 0x7fffu + ((v.u >> 16) & 1u)) >> 16;
    return (short)r;
}

__device__ __forceinline__ void stage16(const void* g, void* l) {
    typedef __attribute__((address_space(1))) const unsigned GA;
    typedef __attribute__((address_space(3))) unsigned LA;
    __builtin_amdgcn_global_load_lds((GA*)(const unsigned*)g, (LA*)(unsigned*)l, 16, 0, 0);
}

// ---------------------------------------------------------------------------
// Cast f32 [R][C] -> bf16 transposed [C][R]  (v2: b128 vectorized writes)
// grid (R/64, C/32), block 256
// ---------------------------------------------------------------------------
__global__ __launch_bounds__(256) void transpose_cast_kernel(
        const float* __restrict__ in, short* __restrict__ out, int R, int C) {
    __shared__ float t[64][33];
    const int r0 = blockIdx.x * 64;
    const int c0 = blockIdx.y * 32;
    const int lrow = threadIdx.x >> 5;   // 0..7
    const int lcol = threadIdx.x & 31;
#pragma unroll
    for (int p = 0; p < 8; ++p)
        t[lrow + 8 * p][lcol] = in[(size_t)(r0 + lrow + 8 * p) * C + c0 + lcol];
    __syncthreads();
    const int oc = threadIdx.x >> 3;     // 0..31: output row (source col)
    const int rb = threadIdx.x & 7;      // 0..7:  8-element r-chunk
    v8s o;
#pragma unroll
    for (int e = 0; e < 8; ++e) o[e] = f2bf(t[rb * 8 + e][oc]);
    *(v8s*)(out + (size_t)(c0 + oc) * R + r0 + rb * 8) = o;
}

// ---------------------------------------------------------------------------
// H = cast_bf16(F) @ W ; blockIdx.y selects (feat_p -> Hp) / (feat_s -> Hs)
// v3: 256-thr blocks, 64 m-rows x all 512 n-cols, grid (128, 2) = 256 blocks.
// F rows are read exactly ONCE device-wide; WT is L2-resident.
// ---------------------------------------------------------------------------
__global__ __launch_bounds__(256) void gemm1_kernel(
        const float* __restrict__ Fp, const float* __restrict__ Fs,
        const short* __restrict__ WT,
        short* __restrict__ Hp, short* __restrict__ Hs) {
    const float* F = blockIdx.y ? Fs : Fp;
    short* H = blockIdx.y ? Hs : Hp;
    const int lane = threadIdx.x & 63;
    const int wid  = threadIdx.x >> 6;          // 0..3
    const int lr = lane & 15, lg = lane >> 4;
    const int r0 = blockIdx.x * 64 + wid * 16;  // gridDim.x = 128

    // A-fragments: 16 rows x K=512, f32 -> bf16 once (64 VGPR)
    v8s a[16];
#pragma unroll
    for (int kk = 0; kk < 16; ++kk) {
        const float* ap = F + (size_t)(r0 + lr) * DIM + kk * 32 + lg * 8;
        float4 f0 = *(const float4*)ap;
        float4 f1 = *(const float4*)(ap + 4);
        v8s t;
        t[0] = f2bf(f0.x); t[1] = f2bf(f0.y); t[2] = f2bf(f0.z); t[3] = f2bf(f0.w);
        t[4] = f2bf(f1.x); t[5] = f2bf(f1.y); t[6] = f2bf(f1.z); t[7] = f2bf(f1.w);
        a[kk] = t;
    }

    for (int ctp = 0; ctp < 16; ++ctp) {
        const int cb = ctp * 32;
        v4f acc0 = {}, acc1 = {};
#pragma unroll
        for (int kk = 0; kk < 16; ++kk) {
            v8s b0 = *(const v8s*)(WT + (size_t)(cb + lr) * DIM + kk * 32 + lg * 8);
            v8s b1 = *(const v8s*)(WT + (size_t)(cb + 16 + lr) * DIM + kk * 32 + lg * 8);
            acc0 = __builtin_amdgcn_mfma_f32_16x16x32_bf16(a[kk], b0, acc0, 0, 0, 0);
            acc1 = __builtin_amdgcn_mfma_f32_16x16x32_bf16(a[kk], b1, acc1, 0, 0, 0);
        }
#pragma unroll
        for (int i = 0; i < 4; ++i) {
            H[(size_t)(r0 + lg * 4 + i) * DIM + cb + lr]      = f2bf(acc0[i]);
            H[(size_t)(r0 + lg * 4 + i) * DIM + cb + 16 + lr] = f2bf(acc1[i]);
        }
    }
}

// ---------------------------------------------------------------------------
// Fused kernel (R9, verified 276 us):
//   ring[2] = two full 64x512 Hs jt-tiles (128 KB, XOR-swizzled storage)
//   Sb[2]   = double-buffered bf16 S-tile
// body(t): BAR; issue stage(t+1); phaseA(t); relu->Sb[t&1];
//          vmcnt(8) [drains bF(t-1), stage stays]; phaseB(t-1); lgkm0;
//          issue bF(t) [rides across BAR]; vmcnt(8) [drains stage, keeps bF].
// Phase A wave = (strip=wid>>1: 16 m-rows, half=wid&1: 32 j-cols), afrag[16].
// Phase B wave owns 64 C-cols.
// ---------------------------------------------------------------------------
#define JSPLIT 2
#define JT_PER_BLOCK (NROWS / 64 / JSPLIT)   // 64 j-tiles of 64

__device__ __forceinline__ void stage_full(const char* __restrict__ HsB,
        char* ringW, int j0, int tid) {
#pragma unroll
    for (int s = 0; s < 8; ++s) {
        const int L = s * 8192 + tid * 16;              // linear LDS byte offset
        const int row = L >> 10;                        // 1024 B per j-row
        const int c = (L & 1023) ^ ((row & 7) << 4);    // inverse swizzle (involution)
        stage16(HsB + ((size_t)(j0 + row) << 10) + c, ringW + L);
    }
}

__device__ __forceinline__ void load_bF(v8s (&bF)[8], const short* __restrict__ FsT,
        int j, int wid, int lr, int lg) {
#pragma unroll
    for (int ct = 0; ct < 4; ++ct)
#pragma unroll
        for (int kc2 = 0; kc2 < 2; ++kc2)
            bF[ct * 2 + kc2] = *(const v8s*)(FsT +
                (size_t)(wid * 64 + ct * 16 + lr) * NROWS + j + kc2 * 32 + lg * 8);
}

__device__ __forceinline__ void phase_b(const short (*SbR)[72], const v8s* bF,
        v4f (&accC)[16], int lr, int lg) {
    __builtin_amdgcn_s_setprio(1);
#pragma unroll
    for (int kc2 = 0; kc2 < 2; ++kc2)
#pragma unroll
        for (int mt = 0; mt < 4; ++mt) {
            v8s aS = *(const v8s*)&SbR[mt * 16 + lr][kc2 * 32 + lg * 8];
#pragma unroll
            for (int ct = 0; ct < 4; ++ct)
                accC[mt * 4 + ct] = __builtin_amdgcn_mfma_f32_16x16x32_bf16(
                    aS, bF[ct * 2 + kc2], accC[mt * 4 + ct], 0, 0, 0);
        }
    __builtin_amdgcn_s_setprio(0);
}

__global__ __launch_bounds__(512, 2) void fused_kernel(
        const short* __restrict__ Hp, const short* __restrict__ Hs,
        const short* __restrict__ FsT, float* __restrict__ Cacc,
        float* __restrict__ ssq) {
    __shared__ __align__(16) short HsL[2][64][512];   // 2 x 64KB ring
    __shared__ __align__(16) short Sb[2][64][72];     // 2 x 9KB S-tile

    const int tid  = threadIdx.x;
    const int lane = tid & 63;
    const int wid  = tid >> 6;
    const int lr = lane & 15, lg = lane >> 4;
    const int strip = wid >> 1;    // m-strip (0..3), 16 rows
    const int half  = wid & 1;     // j-half (0..1), 32 cols

    // XCD-aware swizzle: 256 blocks, 8 XCDs -> contiguous chunks of 32
    const int nwg = gridDim.x * gridDim.y;
    const int bid = blockIdx.x + gridDim.x * blockIdx.y;
    const int cpx = nwg >> 3;
    const int swz = (bid & 7) * cpx + (bid >> 3);
    const int bx = swz % gridDim.x;
    const int by = swz / gridDim.x;

    const int m0  = bx * 64;
    const int jt0 = by * JT_PER_BLOCK;

    // A-fragments: 16 Hp rows (strip) x full K=512 -> 64 VGPR
    v8s afrag[16];
#pragma unroll
    for (int kk = 0; kk < 16; ++kk)
        afrag[kk] = *(const v8s*)(Hp +
            (size_t)(m0 + strip * 16 + lr) * DIM + kk * 32 + lg * 8);

    v4f accC[16] = {};
    v8s bF[8];
    float ssq_l = 0.f;

    stage_full((const char*)Hs, (char*)&HsL[0][0][0], jt0 * 64, tid);
    ASM_VMCNT(0);   // afrag + jt0 staging drained

    const int xo = (lr & 7) << 4;

    for (int t = 0; t < JT_PER_BLOCK; ++t) {
        const int jcur  = (jt0 + t) * 64;
        const int jnext = (t + 1 < JT_PER_BLOCK) ? jcur + 64 : jt0 * 64;
        const char* ringR = (const char*)&HsL[t & 1][0][0];
        char*       ringW = (char*)&HsL[(t + 1) & 1][0][0];

        BAR;   // ring[t&1] staged by all; Sb[(t-1)&1] published; prior readers done
        ASM_FENCE;

        // issue staging for next jt (stays in flight through this body)
        stage_full((const char*)Hs, ringW, jnext, tid);

        // ---- phase A(t): S[strip*16..+16][half*32..+32] over K=512
        v4f s0 = {}, s1 = {};
        {
            const char* rp0 = ringR + (size_t)(half * 32 + lr) * 1024;
            const char* rp1 = rp0 + 16 * 1024;
            __builtin_amdgcn_s_setprio(1);
#pragma unroll
            for (int kk = 0; kk < 16; ++kk) {
                const int off = (kk * 64 + lg * 16) ^ xo;
                v8s hb0 = *(const v8s*)(rp0 + off);
                v8s hb1 = *(const v8s*)(rp1 + off);
                s0 = __builtin_amdgcn_mfma_f32_16x16x32_bf16(afrag[kk], hb0, s0, 0, 0, 0);
                s1 = __builtin_amdgcn_mfma_f32_16x16x32_bf16(afrag[kk], hb1, s1, 0, 0, 0);
            }
            __builtin_amdgcn_s_setprio(0);
        }

        // ---- relu + ssq + Sb[t&1] write
        short (*SbW)[72] = Sb[t & 1];
#pragma unroll
        for (int i = 0; i < 4; ++i) {
            float v0 = fmaxf(s0[i], 0.f), v1 = fmaxf(s1[i], 0.f);
            ssq_l += v0 * v0 + v1 * v1;
            const int r = strip * 16 + lg * 4 + i;
            SbW[r][(half * 2 + 0) * 16 + lr] = f2bf(v0);
            SbW[r][(half * 2 + 1) * 16 + lr] = f2bf(v1);
        }

        // ---- phase B(t-1): bF(t-1) issued last body, fully landed by now
        if (t > 0) {
            ASM_VMCNT(8);   // drains bF(t-1) (oldest 8); stage(t+1) stays
            phase_b(Sb[(t - 1) & 1], bF, accC, lr, lg);
        }
        ASM_LGKM0;          // ring reads + Sb writes drained (publish at next BAR)

        // ---- issue bF(t) for next body's phase B (rides across the barrier)
        ASM_FENCE;
        load_bF(bF, FsT, jcur, wid, lr, lg);
        ASM_VMCNT(8);       // drains stage(t+1) (older); bF(t) stays in flight
    }

    // ---- final phase B for t = JT_PER_BLOCK-1 (bF already in flight)
    BAR;
    ASM_VMCNT(0);
    phase_b(Sb[(JT_PER_BLOCK - 1) & 1], bF, accC, lr, lg);

    // ---- epilogue
    float w = ssq_l;
#pragma unroll
    for (int off = 32; off; off >>= 1) w += __shfl_down(w, off);
    if (lane == 0) atomicAdd(ssq, w);

#pragma unroll
    for (int mt = 0; mt < 4; ++mt)
#pragma unroll
        for (int ct = 0; ct < 4; ++ct)
#pragma unroll
            for (int i = 0; i < 4; ++i)
                atomicAdd(&Cacc[(size_t)(m0 + mt * 16 + lg * 4 + i) * DIM +
                                wid * 64 + ct * 16 + lr],
                          accC[mt * 4 + ct][i]);
}

// ---------------------------------------------------------------------------
__global__ __launch_bounds__(256) void scale_kernel(float* __restrict__ C,
                                                    const float* __restrict__ ssq) {
    const float rs = 1.0f / sqrtf(*ssq);
    const size_t i = (size_t)blockIdx.x * blockDim.x + threadIdx.x;
    float4* p = (float4*)C;
    float4 v = p[i];
    v.x *= rs; v.y *= rs; v.z *= rs; v.w *= rs;
    p[i] = v;
}

// ---------------------------------------------------------------------------
extern "C" void kernel_launch(void* const* d_in, const int* in_sizes, int n_in,
                              void* d_out, int out_size, void* d_ws, size_t ws_size,
                              hipStream_t stream) {
    const float* feat_p   = (const float*)d_in[0];
    const float* feat_s   = (const float*)d_in[1];
    const float* weight_a = (const float*)d_in[2];

    char* ws = (char*)d_ws;
    float* ssqp = (float*)ws;                                  // 4 B
    short* WT   = (short*)(ws + 512);                          // 512 KB
    short* Hp   = (short*)(ws + 512 + 524288);                 // 8 MB
    short* Hs   = (short*)(ws + 512 + 524288 + 8388608);       // 8 MB
    short* FsT  = (short*)(ws + 512 + 524288 + 16777216);      // 8 MB [DIM][NROWS]

    transpose_cast_kernel<<<dim3(DIM / 64, DIM / 32), 256, 0, stream>>>(weight_a, WT, DIM, DIM);
    transpose_cast_kernel<<<dim3(NROWS / 64, DIM / 32), 256, 0, stream>>>(feat_s, FsT, NROWS, DIM);

    gemm1_kernel<<<dim3(NROWS / 64, 2), 256, 0, stream>>>(
        feat_p, feat_s, WT, Hp, Hs);

    hipMemsetAsync(d_out, 0, (size_t)out_size * sizeof(float), stream);
    hipMemsetAsync(ssqp, 0, sizeof(float), stream);

    fused_kernel<<<dim3(NROWS / 64, JSPLIT), 512, 0, stream>>>(Hp, Hs, FsT, (float*)d_out, ssqp);

    scale_kernel<<<(out_size / 4 + 255) / 256, 256, 0, stream>>>((float*)d_out, ssqp);
}